// Round 1
// baseline (115.299 us; speedup 1.0000x reference)
//
#include <hip/hip_runtime.h>
#include <hip/hip_bf16.h>

// N=10000 nodes, F=256, H=256, E=320000 edges.
//
// W1 = [W1a | W1b]:  U' = x @ W1a^T + b1 (bias folded), V = x @ W1b^T
// out[e] = sigmoid(b2 + sum_j relu(U'[row][j] + V[col][j]) * W2[j])
// uv layout (fp8 e4m3, HW cvt): uv[node] = 512 bytes: [0:256]=U', [256:512]=V.
//
// R16 = R15 + FOLDED-H GEMM: both U' and V contract over the SAME x features
// (k=0..255); only the W1 k-half differs. So one block now computes all 512
// uv cols for its 16 nodes from a SINGLE x staging:
//   grid (625,1); wave w covers cols w*128..w*128+127
//   (W1 row base r0=(w&1)*128, k-half hh=w>>1; uv col = hh*256+r0+... = w*128+...)
// vs R15's grid (625,2) which staged the identical x tile twice.
// Effect: x HBM traffic 20->10 MB, staging VALU halved, 64 MFMA/wave (was 32).
// MFMA sequence per output element unchanged -> bit-identical results.
//
// Journal: R6+R14 fused coop kernel -> 288/250us (spill / latency-parked;
// fusion structurally wrong here). R8/R9 sort-for-locality -> 75-96us sort
// >> ~20us gain. R7 deeper edge ILP -> neutral (edge L2 line-bound ~25us).
// R11 fp8 uv: -14.7us. R12 measured gemm+1gap = 28us. R13 single-barrier
// K-loop + 2x blocks: -3us. R15 operand-swap + packed dword stores.
// Harness tax ~47us fill + restores per window.

typedef __attribute__((ext_vector_type(8))) short bf16x8;
typedef __attribute__((ext_vector_type(4))) float f32x4;
typedef __attribute__((ext_vector_type(2))) float f32x2;

__device__ __forceinline__ unsigned short f2bf(float f) {
    __hip_bfloat16 h = __float2bfloat16(f);
    return *reinterpret_cast<unsigned short*>(&h);
}

// ---------------------------------------------------------------------------
// Kernel 0: convert W1 (256x512 fp32) to bf16. Tiny (~2us).
// ---------------------------------------------------------------------------
__global__ __launch_bounds__(256) void convert_w(const float* __restrict__ w1,
                                                 unsigned short* __restrict__ wb,
                                                 int nw4) {
    int i = blockIdx.x * 256 + threadIdx.x;
    if (i < nw4) {
        float4 v = ((const float4*)w1)[i];
        ushort4 o = {f2bf(v.x), f2bf(v.y), f2bf(v.z), f2bf(v.w)};
        ((ushort4*)wb)[i] = o;
    }
}

// ---------------------------------------------------------------------------
// Kernel 1 v8 (folded-h): grid (625,1). Block = 16 nodes x ALL 512 uv cols.
// Stage full 16x256 A-tile (x, fp32->bf16) to LDS ONCE (stride 264: 2-way
// bank alias = free), ONE barrier, barrier-free K-loop.
// MFMA operands SWAPPED: A = W1-frag (m = uv col), B = x-frag (n = node).
// Wave w: W1 row base r0=(w&1)*128, k-half hh=w>>1; n-tile j covers uv cols
// w*128 + j*16 .. +15.
//   W1-frag: wb row (r0 + j*16 + lm), k = hh*256 + kt + lq*8   (16B)
//   x-frag:  As[lm][kt + lq*8]                                 (16B)
//   D: node = m0 + lm; cols = w*128 + j*16 + lq*4 + (0..3)
// Epilogue: bias (waves 0,1 = U half only) + 2x cvt_pk_fp8 -> one dword
// store per n-tile.
// ---------------------------------------------------------------------------
__global__ __launch_bounds__(256) void gemm_mfma(const float* __restrict__ x,
                                                 const unsigned short* __restrict__ wb,
                                                 const float* __restrict__ b1,
                                                 unsigned char* __restrict__ uv,
                                                 int M) {
    __shared__ __align__(16) unsigned short As[16][264];   // 8.25 KB

    const int t    = threadIdx.x;
    const int wave = t >> 6;
    const int lane = t & 63;
    const int lm   = lane & 15;
    const int lq   = lane >> 4;
    const int lk   = lq * 8;
    const int m0   = blockIdx.x * 16;

    // ---- stage A: thread t covers row (t>>4), cols (t&15)*4 + i*64 ----
    {
        const int srow = t >> 4;
        const int scol = (t & 15) * 4;
        const int gr   = m0 + srow;
        const float* xr = x + (size_t)(gr < M ? gr : (M - 1)) * 256;
#pragma unroll
        for (int i = 0; i < 4; ++i) {
            float4 v = *(const float4*)(xr + scol + i * 64);
            ushort4 o = {f2bf(v.x), f2bf(v.y), f2bf(v.z), f2bf(v.w)};
            *(ushort4*)&As[srow][scol + i * 64] = o;
        }
    }
    __syncthreads();

    // Wave's W1 slice: rows r0..r0+127, k-half hh.
    const int hh = wave >> 1;
    const int r0 = (wave & 1) * 128;
    const unsigned short* bpre =
        wb + (size_t)(r0 + lm) * 512 + hh * 256 + lk;

    f32x4 acc[8];
#pragma unroll
    for (int j = 0; j < 8; ++j) acc[j] = f32x4{0.f, 0.f, 0.f, 0.f};

#pragma unroll 4
    for (int kt = 0; kt < 256; kt += 32) {
        bf16x8 xf = *(const bf16x8*)&As[lm][kt + lk];
#pragma unroll
        for (int j = 0; j < 8; ++j) {
            bf16x8 w = *(const bf16x8*)(bpre + (size_t)j * 16 * 512 + kt);
            // swapped: A = W1 (m = uv col), B = x (n = node)
            acc[j] = __builtin_amdgcn_mfma_f32_16x16x32_bf16(w, xf, acc[j], 0, 0, 0);
        }
    }

    // ---- epilogue: node = m0+lm; 4 consecutive cols per n-tile -> dword ----
    const int node = m0 + lm;
    if (node < M) {
        unsigned char* up = uv + (size_t)node * 512 + wave * 128 + lq * 4;
#pragma unroll
        for (int j = 0; j < 8; ++j) {
            float4 bb = (wave < 2)
                          ? *(const float4*)(b1 + wave * 128 + j * 16 + lq * 4)
                          : float4{0.f, 0.f, 0.f, 0.f};
            unsigned int d = __builtin_amdgcn_cvt_pk_fp8_f32(
                acc[j][0] + bb.x, acc[j][1] + bb.y, 0, false);
            d = __builtin_amdgcn_cvt_pk_fp8_f32(
                acc[j][2] + bb.z, acc[j][3] + bb.w, d, true);
            *(unsigned int*)(up + j * 16) = d;
        }
    }
}

// ---------------------------------------------------------------------------
// Kernel 2 (R11, unchanged): edge phase over fp8 uv. 4 edges/batch
// (g=lane>>4 slot, c=lane&15 col chunk); per lane one uint4 (16 fp8) per
// U row + one per V row; two independent batches per iteration; HW decode.
// ---------------------------------------------------------------------------
__global__ __launch_bounds__(256) void edge_kernel(const unsigned char* __restrict__ uv,
                                                   const int* __restrict__ ei,
                                                   const float* __restrict__ w2,
                                                   const float* __restrict__ b2p,
                                                   float* __restrict__ out, int E) {
    const int lane = threadIdx.x & 63;
    const int g = lane >> 4;
    const int c = lane & 15;
    const int wid  = (blockIdx.x * blockDim.x + threadIdx.x) >> 6;
    const int nwav = (gridDim.x * blockDim.x) >> 6;
    const int nb   = E >> 2;

    float w2r[16];
#pragma unroll
    for (int i = 0; i < 4; ++i)
        *(float4*)&w2r[i * 4] = *(const float4*)(w2 + c * 16 + i * 4);
    const float b2 = b2p[0];

    for (int b = wid; b < nb; b += 2 * nwav) {
        const int bB = b + nwav;
        const bool has2 = bB < nb;

        const int e0 = b * 4 + g;
        const int r0 = ei[e0];
        const int c0 = ei[E + e0];
        const int e1 = has2 ? bB * 4 + g : e0;
        const int r1 = ei[e1];
        const int c1 = ei[E + e1];

        uint4 ua = *(const uint4*)(uv + (size_t)r0 * 512 + c * 16);
        uint4 va = *(const uint4*)(uv + (size_t)c0 * 512 + 256 + c * 16);
        uint4 ub = *(const uint4*)(uv + (size_t)r1 * 512 + c * 16);
        uint4 vb = *(const uint4*)(uv + (size_t)c1 * 512 + 256 + c * 16);

        unsigned int uw[4], vw[4];
        float p;

        // ---- batch A ----
        *(uint4*)&uw[0] = ua; *(uint4*)&vw[0] = va;
        {
            float2 p2 = {0.f, 0.f};
#pragma unroll
            for (int w = 0; w < 4; ++w) {
                f32x2 u01 = __builtin_amdgcn_cvt_pk_f32_fp8(uw[w], false);
                f32x2 u23 = __builtin_amdgcn_cvt_pk_f32_fp8(uw[w], true);
                f32x2 v01 = __builtin_amdgcn_cvt_pk_f32_fp8(vw[w], false);
                f32x2 v23 = __builtin_amdgcn_cvt_pk_f32_fp8(vw[w], true);
                float s0 = fmaxf(u01.x + v01.x, 0.f);
                float s1 = fmaxf(u01.y + v01.y, 0.f);
                float s2 = fmaxf(u23.x + v23.x, 0.f);
                float s3 = fmaxf(u23.y + v23.y, 0.f);
                p2.x = fmaf(s0, w2r[4 * w + 0], p2.x);
                p2.y = fmaf(s1, w2r[4 * w + 1], p2.y);
                p2.x = fmaf(s2, w2r[4 * w + 2], p2.x);
                p2.y = fmaf(s3, w2r[4 * w + 3], p2.y);
            }
            p = p2.x + p2.y;
        }
#pragma unroll
        for (int off = 1; off < 16; off <<= 1)
            p += __shfl_xor(p, off, 64);
        if (c == 0) out[e0] = 1.f / (1.f + __expf(-(p + b2)));

        // ---- batch B ----
        if (has2) {
            *(uint4*)&uw[0] = ub; *(uint4*)&vw[0] = vb;
            float2 p2 = {0.f, 0.f};
#pragma unroll
            for (int w = 0; w < 4; ++w) {
                f32x2 u01 = __builtin_amdgcn_cvt_pk_f32_fp8(uw[w], false);
                f32x2 u23 = __builtin_amdgcn_cvt_pk_f32_fp8(uw[w], true);
                f32x2 v01 = __builtin_amdgcn_cvt_pk_f32_fp8(vw[w], false);
                f32x2 v23 = __builtin_amdgcn_cvt_pk_f32_fp8(vw[w], true);
                float s0 = fmaxf(u01.x + v01.x, 0.f);
                float s1 = fmaxf(u01.y + v01.y, 0.f);
                float s2 = fmaxf(u23.x + v23.x, 0.f);
                float s3 = fmaxf(u23.y + v23.y, 0.f);
                p2.x = fmaf(s0, w2r[4 * w + 0], p2.x);
                p2.y = fmaf(s1, w2r[4 * w + 1], p2.y);
                p2.x = fmaf(s2, w2r[4 * w + 2], p2.x);
                p2.y = fmaf(s3, w2r[4 * w + 3], p2.y);
            }
            p = p2.x + p2.y;
#pragma unroll
            for (int off = 1; off < 16; off <<= 1)
                p += __shfl_xor(p, off, 64);
            if (c == 0) out[e1] = 1.f / (1.f + __expf(-(p + b2)));
        }
    }
}

extern "C" void kernel_launch(void* const* d_in, const int* in_sizes, int n_in,
                              void* d_out, int out_size, void* d_ws, size_t ws_size,
                              hipStream_t stream) {
    const float* x  = (const float*)d_in[0];
    const int*   ei = (const int*)d_in[1];
    const float* W1 = (const float*)d_in[2];
    const float* b1 = (const float*)d_in[3];
    const float* W2 = (const float*)d_in[4];
    const float* b2 = (const float*)d_in[5];
    float* out = (float*)d_out;

    const int N = in_sizes[0] / 256;   // 10000
    const int E = in_sizes[1] / 2;     // 320000

    unsigned char*  uv = (unsigned char*)d_ws;            // N*512 fp8 (5.12 MB)
    unsigned short* wb = (unsigned short*)(uv + (size_t)N * 512); // 256KB bf16

    const int nw4 = (256 * 512) / 4;
    convert_w<<<(nw4 + 255) / 256, 256, 0, stream>>>(W1, wb, nw4);

    dim3 g((N + 15) / 16, 1);          // 625 blocks, folded h
    gemm_mfma<<<g, 256, 0, stream>>>(x, wb, b1, uv, N);

    edge_kernel<<<2048, 256, 0, stream>>>(uv, ei, W2, b2, out, E);
}

// Round 2
// 114.911 us; speedup vs baseline: 1.0034x; 1.0034x over previous
//
#include <hip/hip_runtime.h>
#include <hip/hip_bf16.h>

// N=10000 nodes, F=256, H=256, E=320000 edges.
//
// W1 = [W1a | W1b]:  U' = x @ W1a^T + b1 (bias folded), V = x @ W1b^T
// out[e] = sigmoid(b2 + sum_j relu(U'[row][j] + V[col][j]) * W2[j])
// uv layout (fp8 e4m3, HW cvt): uv[node] = 512 bytes: [0:256]=U', [256:512]=V.
//
// R17 = folded-h GEMM with PARALLELISM RESTORED: R16 (grid 625, 4 waves)
// regressed +4.5us because it halved wave count (5000->2500; 19.5->9.8
// waves/CU) -- this gemm is latency-bound on the W1 L2 stream (R13: +2x
// blocks = -3us), so waves matter more than staging instructions.
// R17: 512-thread blocks (8 waves), grid 625 -> 5000 waves again, AND the
// 16x256 x-tile is still staged once per 16 nodes (x HBM 20->10 MB vs R15).
// Wave w covers uv cols w*64..+63 (hh=w>>2, r0=(w&3)*64), 32 MFMA/wave,
// acc 4x f32x4. Per-output MFMA sequence unchanged -> bit-identical.
//
// Journal: R6+R14 fused coop kernel -> 288/250us (spill / latency-parked;
// fusion structurally wrong here). R8/R9 sort-for-locality -> 75-96us sort
// >> ~20us gain. R7 deeper edge ILP -> neutral (edge L2 line-bound ~25us).
// R11 fp8 uv: -14.7us. R12 measured gemm+1gap = 28us. R13 single-barrier
// K-loop + 2x blocks: -3us. R15 operand-swap + packed dword stores (110.8).
// R16 folded-h @4 waves: 115.3 (FAILED: halved waves). Harness tax ~47us.

typedef __attribute__((ext_vector_type(8))) short bf16x8;
typedef __attribute__((ext_vector_type(4))) float f32x4;
typedef __attribute__((ext_vector_type(2))) float f32x2;

__device__ __forceinline__ unsigned short f2bf(float f) {
    __hip_bfloat16 h = __float2bfloat16(f);
    return *reinterpret_cast<unsigned short*>(&h);
}

// ---------------------------------------------------------------------------
// Kernel 0: convert W1 (256x512 fp32) to bf16. Tiny (~2us).
// ---------------------------------------------------------------------------
__global__ __launch_bounds__(256) void convert_w(const float* __restrict__ w1,
                                                 unsigned short* __restrict__ wb,
                                                 int nw4) {
    int i = blockIdx.x * 256 + threadIdx.x;
    if (i < nw4) {
        float4 v = ((const float4*)w1)[i];
        ushort4 o = {f2bf(v.x), f2bf(v.y), f2bf(v.z), f2bf(v.w)};
        ((ushort4*)wb)[i] = o;
    }
}

// ---------------------------------------------------------------------------
// Kernel 1 v9 (folded-h, 8 waves): grid (625,1), block 512.
// Block = 16 nodes x ALL 512 uv cols; x-tile staged to LDS ONCE (stride 264:
// 2-way bank alias = free), ONE barrier, barrier-free K-loop.
// MFMA operands SWAPPED: A = W1-frag (m = uv col), B = x-frag (n = node).
// Wave w: k-half hh=w>>2, W1 row base r0=(w&3)*64; n-tile j covers uv cols
// w*64 + j*16 .. +15.
//   W1-frag: wb row (r0 + j*16 + lm), k = hh*256 + kt + lq*8   (16B)
//   x-frag:  As[lm][kt + lq*8]                                 (16B)
//   D: node = m0 + lm; cols = w*64 + j*16 + lq*4 + (0..3)
// Epilogue: bias (waves 0..3 = U half) + 2x cvt_pk_fp8 -> one dword store
// per n-tile.
// ---------------------------------------------------------------------------
__global__ __launch_bounds__(512) void gemm_mfma(const float* __restrict__ x,
                                                 const unsigned short* __restrict__ wb,
                                                 const float* __restrict__ b1,
                                                 unsigned char* __restrict__ uv,
                                                 int M) {
    __shared__ __align__(16) unsigned short As[16][264];   // 8.25 KB

    const int t    = threadIdx.x;
    const int wave = t >> 6;
    const int lane = t & 63;
    const int lm   = lane & 15;
    const int lq   = lane >> 4;
    const int lk   = lq * 8;
    const int m0   = blockIdx.x * 16;

    // ---- stage A: thread t covers row (t>>5), cols (t&31)*4 + i*128 ----
    {
        const int srow = t >> 5;
        const int scol = (t & 31) * 4;
        const int gr   = m0 + srow;
        const float* xr = x + (size_t)(gr < M ? gr : (M - 1)) * 256;
#pragma unroll
        for (int i = 0; i < 2; ++i) {
            float4 v = *(const float4*)(xr + scol + i * 128);
            ushort4 o = {f2bf(v.x), f2bf(v.y), f2bf(v.z), f2bf(v.w)};
            *(ushort4*)&As[srow][scol + i * 128] = o;
        }
    }
    __syncthreads();

    // Wave's W1 slice: rows r0..r0+63, k-half hh.
    const int hh = wave >> 2;
    const int r0 = (wave & 3) * 64;
    const unsigned short* bpre =
        wb + (size_t)(r0 + lm) * 512 + hh * 256 + lk;

    f32x4 acc[4];
#pragma unroll
    for (int j = 0; j < 4; ++j) acc[j] = f32x4{0.f, 0.f, 0.f, 0.f};

#pragma unroll 4
    for (int kt = 0; kt < 256; kt += 32) {
        bf16x8 xf = *(const bf16x8*)&As[lm][kt + lk];
#pragma unroll
        for (int j = 0; j < 4; ++j) {
            bf16x8 w = *(const bf16x8*)(bpre + (size_t)j * 16 * 512 + kt);
            // swapped: A = W1 (m = uv col), B = x (n = node)
            acc[j] = __builtin_amdgcn_mfma_f32_16x16x32_bf16(w, xf, acc[j], 0, 0, 0);
        }
    }

    // ---- epilogue: node = m0+lm; 4 consecutive cols per n-tile -> dword ----
    const int node = m0 + lm;
    if (node < M) {
        unsigned char* up = uv + (size_t)node * 512 + wave * 64 + lq * 4;
#pragma unroll
        for (int j = 0; j < 4; ++j) {
            float4 bb = (wave < 4)
                          ? *(const float4*)(b1 + wave * 64 + j * 16 + lq * 4)
                          : float4{0.f, 0.f, 0.f, 0.f};
            unsigned int d = __builtin_amdgcn_cvt_pk_fp8_f32(
                acc[j][0] + bb.x, acc[j][1] + bb.y, 0, false);
            d = __builtin_amdgcn_cvt_pk_fp8_f32(
                acc[j][2] + bb.z, acc[j][3] + bb.w, d, true);
            *(unsigned int*)(up + j * 16) = d;
        }
    }
}

// ---------------------------------------------------------------------------
// Kernel 2 (R11, unchanged): edge phase over fp8 uv. 4 edges/batch
// (g=lane>>4 slot, c=lane&15 col chunk); per lane one uint4 (16 fp8) per
// U row + one per V row; two independent batches per iteration; HW decode.
// ---------------------------------------------------------------------------
__global__ __launch_bounds__(256) void edge_kernel(const unsigned char* __restrict__ uv,
                                                   const int* __restrict__ ei,
                                                   const float* __restrict__ w2,
                                                   const float* __restrict__ b2p,
                                                   float* __restrict__ out, int E) {
    const int lane = threadIdx.x & 63;
    const int g = lane >> 4;
    const int c = lane & 15;
    const int wid  = (blockIdx.x * blockDim.x + threadIdx.x) >> 6;
    const int nwav = (gridDim.x * blockDim.x) >> 6;
    const int nb   = E >> 2;

    float w2r[16];
#pragma unroll
    for (int i = 0; i < 4; ++i)
        *(float4*)&w2r[i * 4] = *(const float4*)(w2 + c * 16 + i * 4);
    const float b2 = b2p[0];

    for (int b = wid; b < nb; b += 2 * nwav) {
        const int bB = b + nwav;
        const bool has2 = bB < nb;

        const int e0 = b * 4 + g;
        const int r0 = ei[e0];
        const int c0 = ei[E + e0];
        const int e1 = has2 ? bB * 4 + g : e0;
        const int r1 = ei[e1];
        const int c1 = ei[E + e1];

        uint4 ua = *(const uint4*)(uv + (size_t)r0 * 512 + c * 16);
        uint4 va = *(const uint4*)(uv + (size_t)c0 * 512 + 256 + c * 16);
        uint4 ub = *(const uint4*)(uv + (size_t)r1 * 512 + c * 16);
        uint4 vb = *(const uint4*)(uv + (size_t)c1 * 512 + 256 + c * 16);

        unsigned int uw[4], vw[4];
        float p;

        // ---- batch A ----
        *(uint4*)&uw[0] = ua; *(uint4*)&vw[0] = va;
        {
            float2 p2 = {0.f, 0.f};
#pragma unroll
            for (int w = 0; w < 4; ++w) {
                f32x2 u01 = __builtin_amdgcn_cvt_pk_f32_fp8(uw[w], false);
                f32x2 u23 = __builtin_amdgcn_cvt_pk_f32_fp8(uw[w], true);
                f32x2 v01 = __builtin_amdgcn_cvt_pk_f32_fp8(vw[w], false);
                f32x2 v23 = __builtin_amdgcn_cvt_pk_f32_fp8(vw[w], true);
                float s0 = fmaxf(u01.x + v01.x, 0.f);
                float s1 = fmaxf(u01.y + v01.y, 0.f);
                float s2 = fmaxf(u23.x + v23.x, 0.f);
                float s3 = fmaxf(u23.y + v23.y, 0.f);
                p2.x = fmaf(s0, w2r[4 * w + 0], p2.x);
                p2.y = fmaf(s1, w2r[4 * w + 1], p2.y);
                p2.x = fmaf(s2, w2r[4 * w + 2], p2.x);
                p2.y = fmaf(s3, w2r[4 * w + 3], p2.y);
            }
            p = p2.x + p2.y;
        }
#pragma unroll
        for (int off = 1; off < 16; off <<= 1)
            p += __shfl_xor(p, off, 64);
        if (c == 0) out[e0] = 1.f / (1.f + __expf(-(p + b2)));

        // ---- batch B ----
        if (has2) {
            *(uint4*)&uw[0] = ub; *(uint4*)&vw[0] = vb;
            float2 p2 = {0.f, 0.f};
#pragma unroll
            for (int w = 0; w < 4; ++w) {
                f32x2 u01 = __builtin_amdgcn_cvt_pk_f32_fp8(uw[w], false);
                f32x2 u23 = __builtin_amdgcn_cvt_pk_f32_fp8(uw[w], true);
                f32x2 v01 = __builtin_amdgcn_cvt_pk_f32_fp8(vw[w], false);
                f32x2 v23 = __builtin_amdgcn_cvt_pk_f32_fp8(vw[w], true);
                float s0 = fmaxf(u01.x + v01.x, 0.f);
                float s1 = fmaxf(u01.y + v01.y, 0.f);
                float s2 = fmaxf(u23.x + v23.x, 0.f);
                float s3 = fmaxf(u23.y + v23.y, 0.f);
                p2.x = fmaf(s0, w2r[4 * w + 0], p2.x);
                p2.y = fmaf(s1, w2r[4 * w + 1], p2.y);
                p2.x = fmaf(s2, w2r[4 * w + 2], p2.x);
                p2.y = fmaf(s3, w2r[4 * w + 3], p2.y);
            }
            p = p2.x + p2.y;
#pragma unroll
            for (int off = 1; off < 16; off <<= 1)
                p += __shfl_xor(p, off, 64);
            if (c == 0) out[e1] = 1.f / (1.f + __expf(-(p + b2)));
        }
    }
}

extern "C" void kernel_launch(void* const* d_in, const int* in_sizes, int n_in,
                              void* d_out, int out_size, void* d_ws, size_t ws_size,
                              hipStream_t stream) {
    const float* x  = (const float*)d_in[0];
    const int*   ei = (const int*)d_in[1];
    const float* W1 = (const float*)d_in[2];
    const float* b1 = (const float*)d_in[3];
    const float* W2 = (const float*)d_in[4];
    const float* b2 = (const float*)d_in[5];
    float* out = (float*)d_out;

    const int N = in_sizes[0] / 256;   // 10000
    const int E = in_sizes[1] / 2;     // 320000

    unsigned char*  uv = (unsigned char*)d_ws;            // N*512 fp8 (5.12 MB)
    unsigned short* wb = (unsigned short*)(uv + (size_t)N * 512); // 256KB bf16

    const int nw4 = (256 * 512) / 4;
    convert_w<<<(nw4 + 255) / 256, 256, 0, stream>>>(W1, wb, nw4);

    dim3 g((N + 15) / 16, 1);          // 625 blocks, folded h, 8 waves each
    gemm_mfma<<<g, 512, 0, stream>>>(x, wb, b1, uv, N);

    edge_kernel<<<2048, 256, 0, stream>>>(uv, ei, W2, b2, out, E);
}

// Round 3
// 106.167 us; speedup vs baseline: 1.0860x; 1.0824x over previous
//
#include <hip/hip_runtime.h>
#include <hip/hip_bf16.h>

// N=10000 nodes, F=256, H=256, E=320000 edges.
//
// W1 = [W1a | W1b]:  U' = x @ W1a^T + b1 (bias folded), V = x @ W1b^T
// out[e] = sigmoid(b2 + sum_j relu(U'[row][j] + V[col][j]) * W2[j])
// uv layout (fp8 e4m3, HW cvt): uv[node] = 512 bytes: [0:256]=U', [256:512]=V.
//
// R18 = W1-RESIDENT-IN-LDS gemm, convert_w ELIMINATED.
//   Diagnosis: R16/R17 both lost ~4us with 625-block grids (2.44 blocks/CU,
//   3:2 CU imbalance) regardless of wave count -> grid granularity is a
//   first-order cost. R15's gemm streams W1 from L2 1250x (160 MB, 32
//   latency-exposed L2 loads/wave) -> that is the structural cost.
//   R18: grid 250 blocks x 1024 thr (<=256 CUs: every block co-resident on
//   its own CU, zero block imbalance, 16 waves/CU). Block (h=k-half,
//   c=node-group of 5 tiles; 625=125x5 exact) converts its 256x256 fp32
//   W1-half -> bf16 into 135KB LDS once (replaces convert_w kernel+gap),
//   one barrier, then 20 barrier-free wave-tasks (tile x row-quarter).
//   W1 frags from LDS (69 TB/s, As-pattern 264-pad = 2-way free), x frags
//   per-lane from global + cvt (tile's 16KB x reused 4x by concurrent
//   quarter-waves -> L1). MFMA operand values/order unchanged -> absmax
//   identical.
//
// Journal: R6+R14 fused coop kernel -> 288/250us (spill/latency-parked).
// R8/R9 sort-for-locality -> 75-96us sort >> gain. R7 deeper edge ILP ->
// neutral. R11 fp8 uv: -14.7us. R12 gemm+1gap = 28us. R13 1-barrier+2x
// blocks: -3us. R15 operand-swap + packed stores: 110.8 (BEST). R16 folded-h
// 625x256: 115.3. R17 folded-h 625x512: 114.9 (grid granularity, not waves).
// Harness tax ~47us fill + restores per window.

typedef __attribute__((ext_vector_type(8))) short bf16x8;
typedef __attribute__((ext_vector_type(8))) unsigned short u16x8;
typedef __attribute__((ext_vector_type(4))) float f32x4;
typedef __attribute__((ext_vector_type(2))) float f32x2;

__device__ __forceinline__ unsigned short f2bf(float f) {
    __hip_bfloat16 h = __float2bfloat16(f);
    return *reinterpret_cast<unsigned short*>(&h);
}

// ---------------------------------------------------------------------------
// Kernel 1 (R18): grid 250 = 125 node-groups x 2 k-halves, block 1024 thr.
// Phase 1: convert W1[0:256][h*256 : h*256+256] fp32 -> bf16 into LDS
//          Ws[256][264] (135.2 KB; row stride 264 = As-proven 2-way-free).
// Phase 2: 20 tasks (5 tiles x 4 row-quarters), waves grid-stride (w, w+16).
//   Task (ti,q): nodes m0=(c*5+ti)*16, W1 rows r0=q*64.
//   W1-frag: Ws[r0 + j*16 + lm][kt*32 + lq*8]                (ds_read_b128)
//   x-frag:  x[m0+lm][kt*32 + lq*8 .. +7] fp32 -> cvt bf16   (2x dwordx4)
//   D: node = m0+lm; uv col = h*256 + r0 + j*16 + lq*4 + (0..3)
// Epilogue: bias (h==0) + 2x cvt_pk_fp8 -> one dword store per n-tile.
// ---------------------------------------------------------------------------
__global__ __launch_bounds__(1024) void gemm_lds(const float* __restrict__ x,
                                                 const float* __restrict__ w1,
                                                 const float* __restrict__ b1,
                                                 unsigned char* __restrict__ uv,
                                                 int M) {
    __shared__ __align__(16) unsigned short Ws[256][264];   // 135.2 KB

    const int t    = threadIdx.x;
    const int wave = t >> 6;
    const int lane = t & 63;
    const int lm   = lane & 15;
    const int lq   = lane >> 4;
    const int h    = blockIdx.x & 1;       // k-half
    const int c    = blockIdx.x >> 1;      // node group 0..124 (5 tiles each)

    // ---- phase 1: fill Ws. thread t: row t>>2, cols (t&3)*64 .. +63 ----
    {
        const int row = t >> 2;
        const int col = (t & 3) * 64;
        const float* wr = w1 + (size_t)row * 512 + h * 256 + col;
#pragma unroll
        for (int i = 0; i < 8; ++i) {      // 8 floats -> one 16B LDS write
            float4 a = *(const float4*)(wr + i * 8);
            float4 b = *(const float4*)(wr + i * 8 + 4);
            u16x8 o = {f2bf(a.x), f2bf(a.y), f2bf(a.z), f2bf(a.w),
                       f2bf(b.x), f2bf(b.y), f2bf(b.z), f2bf(b.w)};
            *(u16x8*)&Ws[row][col + i * 8] = o;
        }
    }
    __syncthreads();

    // ---- phase 2: 20 tasks over 16 waves, barrier-free ----
    for (int id = wave; id < 20; id += 16) {
        const int ti = id >> 2;            // tile in group, 0..4
        const int q  = id & 3;             // row quarter
        const int m0 = (c * 5 + ti) * 16;  // node base (<= 9984 at M=10000)
        const int r0 = q * 64;             // W1 row base

        const int gr = m0 + lm;
        const float* xr = x + (size_t)(gr < M ? gr : (M - 1)) * 256 + lq * 8;

        f32x4 acc[4];
#pragma unroll
        for (int j = 0; j < 4; ++j) acc[j] = f32x4{0.f, 0.f, 0.f, 0.f};

#pragma unroll
        for (int kt = 0; kt < 8; ++kt) {
            float4 a = *(const float4*)(xr + kt * 32);
            float4 b = *(const float4*)(xr + kt * 32 + 4);
            bf16x8 xf;
            xf[0] = (short)f2bf(a.x); xf[1] = (short)f2bf(a.y);
            xf[2] = (short)f2bf(a.z); xf[3] = (short)f2bf(a.w);
            xf[4] = (short)f2bf(b.x); xf[5] = (short)f2bf(b.y);
            xf[6] = (short)f2bf(b.z); xf[7] = (short)f2bf(b.w);
#pragma unroll
            for (int j = 0; j < 4; ++j) {
                bf16x8 wf = *(const bf16x8*)&Ws[r0 + j * 16 + lm][kt * 32 + lq * 8];
                // swapped: A = W1 (m = uv col), B = x (n = node)
                acc[j] = __builtin_amdgcn_mfma_f32_16x16x32_bf16(wf, xf, acc[j], 0, 0, 0);
            }
        }

        // ---- epilogue: 4 consecutive uv cols per n-tile -> dword store ----
        const int node = m0 + lm;
        if (node < M) {
            unsigned char* up = uv + (size_t)node * 512 + h * 256 + r0 + lq * 4;
#pragma unroll
            for (int j = 0; j < 4; ++j) {
                float4 bb = (h == 0)
                              ? *(const float4*)(b1 + r0 + j * 16 + lq * 4)
                              : float4{0.f, 0.f, 0.f, 0.f};
                unsigned int d = __builtin_amdgcn_cvt_pk_fp8_f32(
                    acc[j][0] + bb.x, acc[j][1] + bb.y, 0, false);
                d = __builtin_amdgcn_cvt_pk_fp8_f32(
                    acc[j][2] + bb.z, acc[j][3] + bb.w, d, true);
                *(unsigned int*)(up + j * 16) = d;
            }
        }
    }
}

// ---------------------------------------------------------------------------
// Kernel 2 (R11, unchanged): edge phase over fp8 uv. 4 edges/batch
// (g=lane>>4 slot, c=lane&15 col chunk); per lane one uint4 (16 fp8) per
// U row + one per V row; two independent batches per iteration; HW decode.
// ---------------------------------------------------------------------------
__global__ __launch_bounds__(256) void edge_kernel(const unsigned char* __restrict__ uv,
                                                   const int* __restrict__ ei,
                                                   const float* __restrict__ w2,
                                                   const float* __restrict__ b2p,
                                                   float* __restrict__ out, int E) {
    const int lane = threadIdx.x & 63;
    const int g = lane >> 4;
    const int c = lane & 15;
    const int wid  = (blockIdx.x * blockDim.x + threadIdx.x) >> 6;
    const int nwav = (gridDim.x * blockDim.x) >> 6;
    const int nb   = E >> 2;

    float w2r[16];
#pragma unroll
    for (int i = 0; i < 4; ++i)
        *(float4*)&w2r[i * 4] = *(const float4*)(w2 + c * 16 + i * 4);
    const float b2 = b2p[0];

    for (int b = wid; b < nb; b += 2 * nwav) {
        const int bB = b + nwav;
        const bool has2 = bB < nb;

        const int e0 = b * 4 + g;
        const int r0 = ei[e0];
        const int c0 = ei[E + e0];
        const int e1 = has2 ? bB * 4 + g : e0;
        const int r1 = ei[e1];
        const int c1 = ei[E + e1];

        uint4 ua = *(const uint4*)(uv + (size_t)r0 * 512 + c * 16);
        uint4 va = *(const uint4*)(uv + (size_t)c0 * 512 + 256 + c * 16);
        uint4 ub = *(const uint4*)(uv + (size_t)r1 * 512 + c * 16);
        uint4 vb = *(const uint4*)(uv + (size_t)c1 * 512 + 256 + c * 16);

        unsigned int uw[4], vw[4];
        float p;

        // ---- batch A ----
        *(uint4*)&uw[0] = ua; *(uint4*)&vw[0] = va;
        {
            float2 p2 = {0.f, 0.f};
#pragma unroll
            for (int w = 0; w < 4; ++w) {
                f32x2 u01 = __builtin_amdgcn_cvt_pk_f32_fp8(uw[w], false);
                f32x2 u23 = __builtin_amdgcn_cvt_pk_f32_fp8(uw[w], true);
                f32x2 v01 = __builtin_amdgcn_cvt_pk_f32_fp8(vw[w], false);
                f32x2 v23 = __builtin_amdgcn_cvt_pk_f32_fp8(vw[w], true);
                float s0 = fmaxf(u01.x + v01.x, 0.f);
                float s1 = fmaxf(u01.y + v01.y, 0.f);
                float s2 = fmaxf(u23.x + v23.x, 0.f);
                float s3 = fmaxf(u23.y + v23.y, 0.f);
                p2.x = fmaf(s0, w2r[4 * w + 0], p2.x);
                p2.y = fmaf(s1, w2r[4 * w + 1], p2.y);
                p2.x = fmaf(s2, w2r[4 * w + 2], p2.x);
                p2.y = fmaf(s3, w2r[4 * w + 3], p2.y);
            }
            p = p2.x + p2.y;
        }
#pragma unroll
        for (int off = 1; off < 16; off <<= 1)
            p += __shfl_xor(p, off, 64);
        if (c == 0) out[e0] = 1.f / (1.f + __expf(-(p + b2)));

        // ---- batch B ----
        if (has2) {
            *(uint4*)&uw[0] = ub; *(uint4*)&vw[0] = vb;
            float2 p2 = {0.f, 0.f};
#pragma unroll
            for (int w = 0; w < 4; ++w) {
                f32x2 u01 = __builtin_amdgcn_cvt_pk_f32_fp8(uw[w], false);
                f32x2 u23 = __builtin_amdgcn_cvt_pk_f32_fp8(uw[w], true);
                f32x2 v01 = __builtin_amdgcn_cvt_pk_f32_fp8(vw[w], false);
                f32x2 v23 = __builtin_amdgcn_cvt_pk_f32_fp8(vw[w], true);
                float s0 = fmaxf(u01.x + v01.x, 0.f);
                float s1 = fmaxf(u01.y + v01.y, 0.f);
                float s2 = fmaxf(u23.x + v23.x, 0.f);
                float s3 = fmaxf(u23.y + v23.y, 0.f);
                p2.x = fmaf(s0, w2r[4 * w + 0], p2.x);
                p2.y = fmaf(s1, w2r[4 * w + 1], p2.y);
                p2.x = fmaf(s2, w2r[4 * w + 2], p2.x);
                p2.y = fmaf(s3, w2r[4 * w + 3], p2.y);
            }
            p = p2.x + p2.y;
#pragma unroll
            for (int off = 1; off < 16; off <<= 1)
                p += __shfl_xor(p, off, 64);
            if (c == 0) out[e1] = 1.f / (1.f + __expf(-(p + b2)));
        }
    }
}

extern "C" void kernel_launch(void* const* d_in, const int* in_sizes, int n_in,
                              void* d_out, int out_size, void* d_ws, size_t ws_size,
                              hipStream_t stream) {
    const float* x  = (const float*)d_in[0];
    const int*   ei = (const int*)d_in[1];
    const float* W1 = (const float*)d_in[2];
    const float* b1 = (const float*)d_in[3];
    const float* W2 = (const float*)d_in[4];
    const float* b2 = (const float*)d_in[5];
    float* out = (float*)d_out;

    const int N = in_sizes[0] / 256;   // 10000
    const int E = in_sizes[1] / 2;     // 320000

    unsigned char* uv = (unsigned char*)d_ws;   // N*512 fp8 (5.12 MB)

    // 125 node-groups (5 tiles of 16 = 80 nodes each; 625 tiles = 125*5) x 2 halves
    const int ngrp = (N + 79) / 80;
    gemm_lds<<<ngrp * 2, 1024, 0, stream>>>(x, W1, b1, uv, N);

    edge_kernel<<<2048, 256, 0, stream>>>(uv, ei, W2, b2, out, E);
}